// Round 1
// baseline (746.701 us; speedup 1.0000x reference)
//
#include <hip/hip_runtime.h>
#include <math.h>

#define Hdim 1024
#define NHEAD 16
#define HDIM 64
#define BATCH 16
#define SEQ 4
#define CACHE_LEN 8192
#define TOT_LEN 8196  // CACHE_LEN + SEQ

// ---------------- Kernel 1: qkv = x @ W_in + b_in  ([64,1024]@[1024,3072]) ----------------
__global__ __launch_bounds__(256) void qkv_proj(const float* __restrict__ x,
                                                const float* __restrict__ W,
                                                const float* __restrict__ bias,
                                                float* __restrict__ qkv) {
    __shared__ float xs[8][Hdim];
    const int tid = threadIdx.x;
    const int rowBase = blockIdx.y * 8;  // 8 row-groups cover 64 rows
    for (int idx = tid; idx < 8 * Hdim; idx += 256) {
        int r = idx >> 10, c = idx & 1023;
        xs[r][c] = x[(rowBase + r) * Hdim + c];
    }
    __syncthreads();
    const int col = blockIdx.x * 256 + tid;  // grid.x = 12 -> 3072 cols
    float acc[8];
    const float bv = bias[col];
#pragma unroll
    for (int r = 0; r < 8; ++r) acc[r] = bv;
    for (int i = 0; i < Hdim; ++i) {
        const float w = W[i * 3072 + col];
#pragma unroll
        for (int r = 0; r < 8; ++r) acc[r] += xs[r][i] * w;
    }
#pragma unroll
    for (int r = 0; r < 8; ++r) qkv[(size_t)(rowBase + r) * 3072 + col] = acc[r];
}

// ---------------- Kernel 2: fused cache-copy + flash attention ----------------
// grid = 256 blocks (one per (b,h)), 1024 threads: slot = tid>>4 (64 key slots),
// quad = tid&15 (16 x float4 covering hd=64).
__global__ __launch_bounds__(1024) void attn_fused(const float* __restrict__ k_cache,
                                                   const float* __restrict__ v_cache,
                                                   const float* __restrict__ qkv,
                                                   float* __restrict__ k_out,
                                                   float* __restrict__ v_out,
                                                   float* __restrict__ attn_out) {
    const int bh = blockIdx.x;
    const int b = bh >> 4;
    const int h = bh & 15;
    const int tid = threadIdx.x;
    const int slot = tid >> 4;
    const int quad = tid & 15;

    // Preload this thread's q fragment (4 queries x 4 dims), pre-scaled by 1/sqrt(64)
    float q[4][4];
#pragma unroll
    for (int qs = 0; qs < 4; ++qs) {
        const float4 qv = *reinterpret_cast<const float4*>(
            qkv + (size_t)(b * SEQ + qs) * 3072 + h * HDIM + quad * 4);
        q[qs][0] = qv.x * 0.125f;
        q[qs][1] = qv.y * 0.125f;
        q[qs][2] = qv.z * 0.125f;
        q[qs][3] = qv.w * 0.125f;
    }

    const float4* kc = reinterpret_cast<const float4*>(k_cache + (size_t)bh * CACHE_LEN * HDIM);
    const float4* vc = reinterpret_cast<const float4*>(v_cache + (size_t)bh * CACHE_LEN * HDIM);
    float4* ko = reinterpret_cast<float4*>(k_out + (size_t)bh * TOT_LEN * HDIM);
    float4* vo = reinterpret_cast<float4*>(v_out + (size_t)bh * TOT_LEN * HDIM);

    float m[4], l[4], acc[4][4];
#pragma unroll
    for (int qs = 0; qs < 4; ++qs) {
        m[qs] = -INFINITY;
        l[qs] = 0.f;
        acc[qs][0] = acc[qs][1] = acc[qs][2] = acc[qs][3] = 0.f;
    }

    for (int it = 0; it < CACHE_LEN / 64; ++it) {
        const int key = it * 64 + slot;
        const int fi = key * 16 + quad;
        const float4 k4 = kc[fi];
        const float4 v4 = vc[fi];
        ko[fi] = k4;
        vo[fi] = v4;
        float s[4];
#pragma unroll
        for (int qs = 0; qs < 4; ++qs)
            s[qs] = q[qs][0] * k4.x + q[qs][1] * k4.y + q[qs][2] * k4.z + q[qs][3] * k4.w;
#pragma unroll
        for (int off = 1; off < 16; off <<= 1) {
#pragma unroll
            for (int qs = 0; qs < 4; ++qs) s[qs] += __shfl_xor(s[qs], off, 64);
        }
#pragma unroll
        for (int qs = 0; qs < 4; ++qs) {
            const float sv = s[qs];
            if (sv > m[qs]) {
                const float corr = __expf(m[qs] - sv);
                m[qs] = sv;
                l[qs] *= corr;
                acc[qs][0] *= corr;
                acc[qs][1] *= corr;
                acc[qs][2] *= corr;
                acc[qs][3] *= corr;
            }
            const float w = __expf(sv - m[qs]);
            l[qs] += w;
            acc[qs][0] += w * v4.x;
            acc[qs][1] += w * v4.y;
            acc[qs][2] += w * v4.z;
            acc[qs][3] += w * v4.w;
        }
    }

    // Tail: 4 new keys/values from qkv (slots 0..3), also written to the output caches
    if (slot < 4) {
        const int key = CACHE_LEN + slot;
        const int fi = key * 16 + quad;
        const float4 k4 = *reinterpret_cast<const float4*>(
            qkv + (size_t)(b * SEQ + slot) * 3072 + 1024 + h * HDIM + quad * 4);
        const float4 v4 = *reinterpret_cast<const float4*>(
            qkv + (size_t)(b * SEQ + slot) * 3072 + 2048 + h * HDIM + quad * 4);
        ko[fi] = k4;
        vo[fi] = v4;
        float s[4];
#pragma unroll
        for (int qs = 0; qs < 4; ++qs)
            s[qs] = q[qs][0] * k4.x + q[qs][1] * k4.y + q[qs][2] * k4.z + q[qs][3] * k4.w;
#pragma unroll
        for (int off = 1; off < 16; off <<= 1) {
#pragma unroll
            for (int qs = 0; qs < 4; ++qs) s[qs] += __shfl_xor(s[qs], off, 64);
        }
#pragma unroll
        for (int qs = 0; qs < 4; ++qs) {
            const float sv = s[qs];
            if (sv > m[qs]) {
                const float corr = __expf(m[qs] - sv);
                m[qs] = sv;
                l[qs] *= corr;
                acc[qs][0] *= corr;
                acc[qs][1] *= corr;
                acc[qs][2] *= corr;
                acc[qs][3] *= corr;
            }
            const float w = __expf(sv - m[qs]);
            l[qs] += w;
            acc[qs][0] += w * v4.x;
            acc[qs][1] += w * v4.y;
            acc[qs][2] += w * v4.z;
            acc[qs][3] += w * v4.w;
        }
    }

    // ---- merge 64 per-slot partials (log-sum-exp) ----
    __shared__ float red_m[64][4];
    __shared__ float red_l[64][4];
    __shared__ float red_acc[64][64];
    __shared__ float red_part[4][64];

    if (quad == 0) {
#pragma unroll
        for (int qs = 0; qs < 4; ++qs) red_m[slot][qs] = m[qs];
    }
    __syncthreads();
    float M[4];
#pragma unroll
    for (int qs = 0; qs < 4; ++qs) {
        float mm = -INFINITY;
        for (int s2 = 0; s2 < 64; ++s2) mm = fmaxf(mm, red_m[s2][qs]);
        M[qs] = mm;
    }
    float scale[4];
#pragma unroll
    for (int qs = 0; qs < 4; ++qs) {
        scale[qs] = __expf(m[qs] - M[qs]);
        acc[qs][0] *= scale[qs];
        acc[qs][1] *= scale[qs];
        acc[qs][2] *= scale[qs];
        acc[qs][3] *= scale[qs];
    }
    if (quad == 0) {
#pragma unroll
        for (int qs = 0; qs < 4; ++qs) red_l[slot][qs] = l[qs] * scale[qs];
    }
    __syncthreads();
    float L[4];
#pragma unroll
    for (int qs = 0; qs < 4; ++qs) {
        float sum = 0.f;
        for (int s2 = 0; s2 < 64; ++s2) sum += red_l[s2][qs];
        L[qs] = sum;
    }

    for (int qs = 0; qs < 4; ++qs) {
        __syncthreads();
        *reinterpret_cast<float4*>(&red_acc[slot][quad * 4]) =
            make_float4(acc[qs][0], acc[qs][1], acc[qs][2], acc[qs][3]);
        __syncthreads();
        if (tid < 256) {
            const int dim = tid & 63;
            const int part = tid >> 6;
            float sum = 0.f;
            for (int s2 = 0; s2 < 16; ++s2) sum += red_acc[part * 16 + s2][dim];
            red_part[part][dim] = sum;
        }
        __syncthreads();
        if (tid < 64) {
            const float sum = red_part[0][tid] + red_part[1][tid] + red_part[2][tid] + red_part[3][tid];
            attn_out[(size_t)(b * SEQ + qs) * Hdim + h * HDIM + tid] = sum / L[qs];
        }
    }
}

// ---------------- Kernel 3: out = attn @ W_out + b_out  ([64,1024]@[1024,1024]) ----------------
__global__ __launch_bounds__(256) void out_proj(const float* __restrict__ a,
                                                const float* __restrict__ W,
                                                const float* __restrict__ bias,
                                                float* __restrict__ out) {
    __shared__ float xs[8][Hdim];
    const int tid = threadIdx.x;
    const int rowBase = blockIdx.y * 8;
    for (int idx = tid; idx < 8 * Hdim; idx += 256) {
        int r = idx >> 10, c = idx & 1023;
        xs[r][c] = a[(rowBase + r) * Hdim + c];
    }
    __syncthreads();
    const int col = blockIdx.x * 256 + tid;  // grid.x = 4 -> 1024 cols
    float acc[8];
    const float bv = bias[col];
#pragma unroll
    for (int r = 0; r < 8; ++r) acc[r] = bv;
    for (int i = 0; i < Hdim; ++i) {
        const float w = W[i * Hdim + col];
#pragma unroll
        for (int r = 0; r < 8; ++r) acc[r] += xs[r][i] * w;
    }
#pragma unroll
    for (int r = 0; r < 8; ++r) out[(size_t)(rowBase + r) * Hdim + col] = acc[r];
}

extern "C" void kernel_launch(void* const* d_in, const int* in_sizes, int n_in,
                              void* d_out, int out_size, void* d_ws, size_t ws_size,
                              hipStream_t stream) {
    const float* x       = (const float*)d_in[0];
    const float* k_cache = (const float*)d_in[1];
    const float* v_cache = (const float*)d_in[2];
    const float* W_in    = (const float*)d_in[3];
    const float* b_in    = (const float*)d_in[4];
    const float* W_out   = (const float*)d_in[5];
    const float* b_out   = (const float*)d_in[6];

    float* out   = (float*)d_out;                                   // [16,4,1024]
    float* k_out = out + (size_t)BATCH * SEQ * Hdim;                // [16,16,8196,64]
    float* v_out = k_out + (size_t)BATCH * NHEAD * TOT_LEN * HDIM;  // [16,16,8196,64]

    float* ws_qkv  = (float*)d_ws;             // [64, 3072]
    float* ws_attn = ws_qkv + 64 * 3072;       // [64, 1024]

    qkv_proj<<<dim3(12, 8), 256, 0, stream>>>(x, W_in, b_in, ws_qkv);
    attn_fused<<<dim3(256), 1024, 0, stream>>>(k_cache, v_cache, ws_qkv, k_out, v_out, ws_attn);
    out_proj<<<dim3(4, 8), 256, 0, stream>>>(ws_attn, W_out, b_out, out);
}

// Round 3
// 655.993 us; speedup vs baseline: 1.1383x; 1.1383x over previous
//
#include <hip/hip_runtime.h>
#include <math.h>

#define Hdim 1024
#define NHEAD 16
#define HDIM 64
#define BATCH 16
#define SEQ 4
#define CACHE_LEN 8192
#define TOT_LEN 8196  // CACHE_LEN + SEQ

typedef float f4 __attribute__((ext_vector_type(4)));  // NT-builtin-compatible float4

// 16-lane (row) sum reduction via DPP — full-rate VALU, no DS pipe.
// Stages: quad_perm xor1 (0xB1), quad_perm xor2 (0x4E), row_ror:4 (0x124), row_ror:8 (0x128).
__device__ __forceinline__ float row16_reduce(float x) {
    int t;
    t = __builtin_amdgcn_update_dpp(0, __float_as_int(x), 0xB1, 0xF, 0xF, true);
    x += __int_as_float(t);
    t = __builtin_amdgcn_update_dpp(0, __float_as_int(x), 0x4E, 0xF, 0xF, true);
    x += __int_as_float(t);
    t = __builtin_amdgcn_update_dpp(0, __float_as_int(x), 0x124, 0xF, 0xF, true);
    x += __int_as_float(t);
    t = __builtin_amdgcn_update_dpp(0, __float_as_int(x), 0x128, 0xF, 0xF, true);
    x += __int_as_float(t);
    return x;
}

// ---------------- Kernel 1: qkv = x @ W_in + b_in  ([64,1024]@[1024,3072]) ----------------
__global__ __launch_bounds__(256) void qkv_proj(const float* __restrict__ x,
                                                const float* __restrict__ W,
                                                const float* __restrict__ bias,
                                                float* __restrict__ qkv) {
    __shared__ float xs[8][Hdim];
    const int tid = threadIdx.x;
    const int rowBase = blockIdx.y * 8;
    for (int idx = tid; idx < 8 * Hdim; idx += 256) {
        int r = idx >> 10, c = idx & 1023;
        xs[r][c] = x[(rowBase + r) * Hdim + c];
    }
    __syncthreads();
    const int col = blockIdx.x * 256 + tid;  // grid.x = 12 -> 3072 cols
    float acc[8];
    const float bv = bias[col];
#pragma unroll
    for (int r = 0; r < 8; ++r) acc[r] = bv;
#pragma unroll 4
    for (int i = 0; i < Hdim; ++i) {
        const float w = W[i * 3072 + col];
#pragma unroll
        for (int r = 0; r < 8; ++r) acc[r] += xs[r][i] * w;
    }
#pragma unroll
    for (int r = 0; r < 8; ++r) qkv[(size_t)(rowBase + r) * 3072 + col] = acc[r];
}

// ---------------- Kernel 2: fused cache-copy + flash attention ----------------
// grid = 256 blocks (one per (b,h)), 1024 threads: slot = tid>>4 (64 key slots),
// quad = tid&15 (16 x f4 covering hd=64). Unroll x4 key-tiles per iteration:
// 8 NT loads -> 8 NT stores -> DPP dots -> grouped branch-free online softmax.
__global__ __launch_bounds__(1024) void attn_fused(const float* __restrict__ k_cache,
                                                   const float* __restrict__ v_cache,
                                                   const float* __restrict__ qkv,
                                                   float* __restrict__ k_out,
                                                   float* __restrict__ v_out,
                                                   float* __restrict__ attn_out) {
    const int bh = blockIdx.x;
    const int b = bh >> 4;
    const int h = bh & 15;
    const int tid = threadIdx.x;
    const int slot = tid >> 4;
    const int quad = tid & 15;

    // q fragments (4 queries x 4 dims), pre-scaled by 1/sqrt(64)
    float q[4][4];
#pragma unroll
    for (int qs = 0; qs < 4; ++qs) {
        const f4 qv = *reinterpret_cast<const f4*>(
            qkv + (size_t)(b * SEQ + qs) * 3072 + h * HDIM + quad * 4);
        q[qs][0] = qv.x * 0.125f;
        q[qs][1] = qv.y * 0.125f;
        q[qs][2] = qv.z * 0.125f;
        q[qs][3] = qv.w * 0.125f;
    }

    const f4* kc = reinterpret_cast<const f4*>(k_cache + (size_t)bh * CACHE_LEN * HDIM);
    const f4* vc = reinterpret_cast<const f4*>(v_cache + (size_t)bh * CACHE_LEN * HDIM);
    f4* ko = reinterpret_cast<f4*>(k_out + (size_t)bh * TOT_LEN * HDIM);
    f4* vo = reinterpret_cast<f4*>(v_out + (size_t)bh * TOT_LEN * HDIM);

    float m[4], l[4], acc[4][4];
#pragma unroll
    for (int qs = 0; qs < 4; ++qs) {
        m[qs] = -INFINITY;
        l[qs] = 0.f;
        acc[qs][0] = acc[qs][1] = acc[qs][2] = acc[qs][3] = 0.f;
    }

    for (int g = 0; g < CACHE_LEN / 256; ++g) {  // 32 groups of 4 tiles (256 keys)
        f4 kk[4], vv[4];
        int fi[4];
#pragma unroll
        for (int j = 0; j < 4; ++j) {
            const int key = g * 256 + j * 64 + slot;
            fi[j] = key * 16 + quad;
            kk[j] = __builtin_nontemporal_load(kc + fi[j]);
        }
#pragma unroll
        for (int j = 0; j < 4; ++j) vv[j] = __builtin_nontemporal_load(vc + fi[j]);
#pragma unroll
        for (int j = 0; j < 4; ++j) __builtin_nontemporal_store(kk[j], ko + fi[j]);
#pragma unroll
        for (int j = 0; j < 4; ++j) __builtin_nontemporal_store(vv[j], vo + fi[j]);

        float s[4][4];
#pragma unroll
        for (int j = 0; j < 4; ++j) {
#pragma unroll
            for (int qs = 0; qs < 4; ++qs) {
                float d = q[qs][0] * kk[j].x + q[qs][1] * kk[j].y + q[qs][2] * kk[j].z +
                          q[qs][3] * kk[j].w;
                s[j][qs] = row16_reduce(d);
            }
        }

#pragma unroll
        for (int qs = 0; qs < 4; ++qs) {
            const float tmax =
                fmaxf(fmaxf(s[0][qs], s[1][qs]), fmaxf(s[2][qs], s[3][qs]));
            const float mn = fmaxf(m[qs], tmax);
            const float corr = __expf(m[qs] - mn);
            m[qs] = mn;
            const float w0 = __expf(s[0][qs] - mn);
            const float w1 = __expf(s[1][qs] - mn);
            const float w2 = __expf(s[2][qs] - mn);
            const float w3 = __expf(s[3][qs] - mn);
            l[qs] = l[qs] * corr + ((w0 + w1) + (w2 + w3));
            acc[qs][0] = acc[qs][0] * corr + w0 * vv[0].x + w1 * vv[1].x + w2 * vv[2].x + w3 * vv[3].x;
            acc[qs][1] = acc[qs][1] * corr + w0 * vv[0].y + w1 * vv[1].y + w2 * vv[2].y + w3 * vv[3].y;
            acc[qs][2] = acc[qs][2] * corr + w0 * vv[0].z + w1 * vv[1].z + w2 * vv[2].z + w3 * vv[3].z;
            acc[qs][3] = acc[qs][3] * corr + w0 * vv[0].w + w1 * vv[1].w + w2 * vv[2].w + w3 * vv[3].w;
        }
    }

    // Tail: 4 new keys/values from qkv (slots 0..3), also written to the output caches
    if (slot < 4) {
        const int key = CACHE_LEN + slot;
        const int fi = key * 16 + quad;
        const f4 k4 = *reinterpret_cast<const f4*>(
            qkv + (size_t)(b * SEQ + slot) * 3072 + 1024 + h * HDIM + quad * 4);
        const f4 v4 = *reinterpret_cast<const f4*>(
            qkv + (size_t)(b * SEQ + slot) * 3072 + 2048 + h * HDIM + quad * 4);
        ko[fi] = k4;
        vo[fi] = v4;
        float s[4];
#pragma unroll
        for (int qs = 0; qs < 4; ++qs) {
            float d = q[qs][0] * k4.x + q[qs][1] * k4.y + q[qs][2] * k4.z + q[qs][3] * k4.w;
            s[qs] = row16_reduce(d);
        }
#pragma unroll
        for (int qs = 0; qs < 4; ++qs) {
            const float mn = fmaxf(m[qs], s[qs]);
            const float corr = __expf(m[qs] - mn);
            const float w = __expf(s[qs] - mn);
            m[qs] = mn;
            l[qs] = l[qs] * corr + w;
            acc[qs][0] = acc[qs][0] * corr + w * v4.x;
            acc[qs][1] = acc[qs][1] * corr + w * v4.y;
            acc[qs][2] = acc[qs][2] * corr + w * v4.z;
            acc[qs][3] = acc[qs][3] * corr + w * v4.w;
        }
    }

    // ---- merge 64 per-slot partials (log-sum-exp) ----
    __shared__ float red_m[64][4];
    __shared__ float red_l[64][4];
    __shared__ float red_acc[64][64];
    __shared__ float red_part[4][64];

    if (quad == 0) {
#pragma unroll
        for (int qs = 0; qs < 4; ++qs) red_m[slot][qs] = m[qs];
    }
    __syncthreads();
    float M[4];
#pragma unroll
    for (int qs = 0; qs < 4; ++qs) {
        float mm = -INFINITY;
        for (int s2 = 0; s2 < 64; ++s2) mm = fmaxf(mm, red_m[s2][qs]);
        M[qs] = mm;
    }
    float scale[4];
#pragma unroll
    for (int qs = 0; qs < 4; ++qs) {
        scale[qs] = __expf(m[qs] - M[qs]);
        acc[qs][0] *= scale[qs];
        acc[qs][1] *= scale[qs];
        acc[qs][2] *= scale[qs];
        acc[qs][3] *= scale[qs];
    }
    if (quad == 0) {
#pragma unroll
        for (int qs = 0; qs < 4; ++qs) red_l[slot][qs] = l[qs] * scale[qs];
    }
    __syncthreads();
    float L[4];
#pragma unroll
    for (int qs = 0; qs < 4; ++qs) {
        float sum = 0.f;
        for (int s2 = 0; s2 < 64; ++s2) sum += red_l[s2][qs];
        L[qs] = sum;
    }

    for (int qs = 0; qs < 4; ++qs) {
        __syncthreads();
        *reinterpret_cast<f4*>(&red_acc[slot][quad * 4]) =
            (f4){acc[qs][0], acc[qs][1], acc[qs][2], acc[qs][3]};
        __syncthreads();
        if (tid < 256) {
            const int dim = tid & 63;
            const int part = tid >> 6;
            float sum = 0.f;
            for (int s2 = 0; s2 < 16; ++s2) sum += red_acc[part * 16 + s2][dim];
            red_part[part][dim] = sum;
        }
        __syncthreads();
        if (tid < 64) {
            const float sum = red_part[0][tid] + red_part[1][tid] + red_part[2][tid] + red_part[3][tid];
            attn_out[(size_t)(b * SEQ + qs) * Hdim + h * HDIM + tid] = sum / L[qs];
        }
    }
}

// ---------------- Kernel 3: out = attn @ W_out + b_out  ([64,1024]@[1024,1024]) ----------------
__global__ __launch_bounds__(256) void out_proj(const float* __restrict__ a,
                                                const float* __restrict__ W,
                                                const float* __restrict__ bias,
                                                float* __restrict__ out) {
    __shared__ float xs[8][Hdim];
    const int tid = threadIdx.x;
    const int rowBase = blockIdx.y * 8;
    for (int idx = tid; idx < 8 * Hdim; idx += 256) {
        int r = idx >> 10, c = idx & 1023;
        xs[r][c] = a[(rowBase + r) * Hdim + c];
    }
    __syncthreads();
    const int col = blockIdx.x * 256 + tid;  // grid.x = 4 -> 1024 cols
    float acc[8];
    const float bv = bias[col];
#pragma unroll
    for (int r = 0; r < 8; ++r) acc[r] = bv;
#pragma unroll 4
    for (int i = 0; i < Hdim; ++i) {
        const float w = W[i * Hdim + col];
#pragma unroll
        for (int r = 0; r < 8; ++r) acc[r] += xs[r][i] * w;
    }
#pragma unroll
    for (int r = 0; r < 8; ++r) out[(size_t)(rowBase + r) * Hdim + col] = acc[r];
}

extern "C" void kernel_launch(void* const* d_in, const int* in_sizes, int n_in,
                              void* d_out, int out_size, void* d_ws, size_t ws_size,
                              hipStream_t stream) {
    const float* x       = (const float*)d_in[0];
    const float* k_cache = (const float*)d_in[1];
    const float* v_cache = (const float*)d_in[2];
    const float* W_in    = (const float*)d_in[3];
    const float* b_in    = (const float*)d_in[4];
    const float* W_out   = (const float*)d_in[5];
    const float* b_out   = (const float*)d_in[6];

    float* out   = (float*)d_out;                                   // [16,4,1024]
    float* k_out = out + (size_t)BATCH * SEQ * Hdim;                // [16,16,8196,64]
    float* v_out = k_out + (size_t)BATCH * NHEAD * TOT_LEN * HDIM;  // [16,16,8196,64]

    float* ws_qkv  = (float*)d_ws;             // [64, 3072]
    float* ws_attn = ws_qkv + 64 * 3072;       // [64, 1024]

    qkv_proj<<<dim3(12, 8), 256, 0, stream>>>(x, W_in, b_in, ws_qkv);
    attn_fused<<<dim3(256), 1024, 0, stream>>>(k_cache, v_cache, ws_qkv, k_out, v_out, ws_attn);
    out_proj<<<dim3(4, 8), 256, 0, stream>>>(ws_attn, W_out, b_out, out);
}

// Round 4
// 466.454 us; speedup vs baseline: 1.6008x; 1.4063x over previous
//
#include <hip/hip_runtime.h>
#include <math.h>

#define NHEAD 16
#define HDIM 64
#define BATCH 16
#define SEQ 4
#define CACHE_LEN 8192
#define TOT_LEN 8196   // CACHE_LEN + SEQ
#define S_STRIDE 8200  // f4 slots per bh in score workspace (>= TOT_LEN, 16B aligned)

typedef float f4 __attribute__((ext_vector_type(4)));

// 16-lane (row) sum reduction via DPP — full-rate VALU, no DS pipe.
__device__ __forceinline__ float row16_reduce(float x) {
    int t;
    t = __builtin_amdgcn_update_dpp(0, __float_as_int(x), 0xB1, 0xF, 0xF, true);
    x += __int_as_float(t);
    t = __builtin_amdgcn_update_dpp(0, __float_as_int(x), 0x4E, 0xF, 0xF, true);
    x += __int_as_float(t);
    t = __builtin_amdgcn_update_dpp(0, __float_as_int(x), 0x124, 0xF, 0xF, true);
    x += __int_as_float(t);
    t = __builtin_amdgcn_update_dpp(0, __float_as_int(x), 0x128, 0xF, 0xF, true);
    x += __int_as_float(t);
    return x;
}

// ---------------- GEMM: out[64 x N] = x[64 x 1024] @ W[1024 x N] + bias ----------------
// grid (N/64, 8), block 256: col = tid&63, kseg = tid>>6 (4 segments x 256 K each).
template <int N>
__global__ __launch_bounds__(256) void gemm64(const float* __restrict__ x,
                                              const float* __restrict__ W,
                                              const float* __restrict__ bias,
                                              float* __restrict__ out) {
    __shared__ float xs[8][1024];
    __shared__ float red[4][8][64];
    const int tid = threadIdx.x;
    const int colBase = blockIdx.x * 64;
    const int rowBase = blockIdx.y * 8;
    for (int idx = tid; idx < 8 * 1024; idx += 256) {
        xs[idx >> 10][idx & 1023] = x[(size_t)(rowBase + (idx >> 10)) * 1024 + (idx & 1023)];
    }
    __syncthreads();
    const int col = tid & 63;
    const int kseg = tid >> 6;
    float acc[8] = {0.f, 0.f, 0.f, 0.f, 0.f, 0.f, 0.f, 0.f};
    const float* Wp = W + (size_t)colBase + col;
    const int k0 = kseg * 256;
#pragma unroll 4
    for (int k = k0; k < k0 + 256; ++k) {
        const float w = Wp[(size_t)k * N];
#pragma unroll
        for (int r = 0; r < 8; ++r) acc[r] += xs[r][k] * w;
    }
#pragma unroll
    for (int r = 0; r < 8; ++r) red[kseg][r][col] = acc[r];
    __syncthreads();
    if (kseg == 0) {
        const float bv = bias[colBase + col];
#pragma unroll
        for (int r = 0; r < 8; ++r) {
            out[(size_t)(rowBase + r) * N + colBase + col] =
                red[0][r][col] + red[1][r][col] + red[2][r][col] + red[3][r][col] + bv;
        }
    }
}

// ---------------- k-pass: copy k_cache -> k_out, scores -> s_ws, final (m,l) -> ml_ws --------
// grid 256 (one per (b,h)), 1024 threads: slot = tid>>4 (64 keys), quad = tid&15.
__global__ __launch_bounds__(1024) void k_pass(const float* __restrict__ k_cache,
                                               const float* __restrict__ qkv,
                                               float* __restrict__ k_out,
                                               f4* __restrict__ s_ws,
                                               float* __restrict__ ml_ws) {
    const int bh = blockIdx.x;
    const int b = bh >> 4;
    const int h = bh & 15;
    const int tid = threadIdx.x;
    const int slot = tid >> 4;
    const int quad = tid & 15;

    float q[4][4];
#pragma unroll
    for (int qs = 0; qs < 4; ++qs) {
        const f4 qv = *reinterpret_cast<const f4*>(
            qkv + (size_t)(b * SEQ + qs) * 3072 + h * HDIM + quad * 4);
        q[qs][0] = qv.x * 0.125f;
        q[qs][1] = qv.y * 0.125f;
        q[qs][2] = qv.z * 0.125f;
        q[qs][3] = qv.w * 0.125f;
    }

    const f4* kc = reinterpret_cast<const f4*>(k_cache + (size_t)bh * CACHE_LEN * HDIM);
    f4* ko = reinterpret_cast<f4*>(k_out + (size_t)bh * TOT_LEN * HDIM);
    f4* sb = s_ws + (size_t)bh * S_STRIDE;

    float m[4], l[4];
#pragma unroll
    for (int qs = 0; qs < 4; ++qs) {
        m[qs] = -INFINITY;
        l[qs] = 0.f;
    }

    for (int g = 0; g < CACHE_LEN / 256; ++g) {  // 32 iterations of 256 keys
        f4 kk[4];
        int fi[4];
#pragma unroll
        for (int j = 0; j < 4; ++j) {
            const int key = g * 256 + j * 64 + slot;
            fi[j] = key * 16 + quad;
            kk[j] = __builtin_nontemporal_load(kc + fi[j]);
        }
#pragma unroll
        for (int j = 0; j < 4; ++j) __builtin_nontemporal_store(kk[j], ko + fi[j]);

        float s[4][4];
#pragma unroll
        for (int j = 0; j < 4; ++j) {
#pragma unroll
            for (int qs = 0; qs < 4; ++qs) {
                float d = q[qs][0] * kk[j].x + q[qs][1] * kk[j].y + q[qs][2] * kk[j].z +
                          q[qs][3] * kk[j].w;
                s[j][qs] = row16_reduce(d);
            }
        }
#pragma unroll
        for (int qs = 0; qs < 4; ++qs) {
            const float tmax = fmaxf(fmaxf(s[0][qs], s[1][qs]), fmaxf(s[2][qs], s[3][qs]));
            const float mn = fmaxf(m[qs], tmax);
            const float corr = __expf(m[qs] - mn);
            m[qs] = mn;
            l[qs] = l[qs] * corr + ((__expf(s[0][qs] - mn) + __expf(s[1][qs] - mn)) +
                                    (__expf(s[2][qs] - mn) + __expf(s[3][qs] - mn)));
        }
        if (quad == 0) {
#pragma unroll
            for (int j = 0; j < 4; ++j) {
                __builtin_nontemporal_store((f4){s[j][0], s[j][1], s[j][2], s[j][3]},
                                            sb + g * 256 + j * 64 + slot);
            }
        }
    }

    // Tail: 4 new keys from qkv (wave 0 only: slot 0..3 == tid 0..63)
    if (slot < 4) {
        const int key = CACHE_LEN + slot;
        const f4 k4 = *reinterpret_cast<const f4*>(
            qkv + (size_t)(b * SEQ + slot) * 3072 + 1024 + h * HDIM + quad * 4);
        ko[key * 16 + quad] = k4;
        float s[4];
#pragma unroll
        for (int qs = 0; qs < 4; ++qs) {
            float d = q[qs][0] * k4.x + q[qs][1] * k4.y + q[qs][2] * k4.z + q[qs][3] * k4.w;
            s[qs] = row16_reduce(d);
        }
#pragma unroll
        for (int qs = 0; qs < 4; ++qs) {
            const float mn = fmaxf(m[qs], s[qs]);
            const float corr = __expf(m[qs] - mn);
            m[qs] = mn;
            l[qs] = l[qs] * corr + __expf(s[qs] - mn);
        }
        if (quad == 0) sb[CACHE_LEN + slot] = (f4){s[0], s[1], s[2], s[3]};
    }

    // Merge (m,l) across the 64 slots; write global m, l for this bh.
    __shared__ float rm[64][4];
    __shared__ float rl[64][4];
    if (quad == 0) {
#pragma unroll
        for (int qs = 0; qs < 4; ++qs) {
            rm[slot][qs] = m[qs];
            rl[slot][qs] = l[qs];
        }
    }
    __syncthreads();
    if (tid < 4) {
        float M = -INFINITY;
        for (int s2 = 0; s2 < 64; ++s2) M = fmaxf(M, rm[s2][tid]);
        float L = 0.f;
        for (int s2 = 0; s2 < 64; ++s2) L += rl[s2][tid] * __expf(rm[s2][tid] - M);
        ml_ws[bh * 8 + tid] = M;
        ml_ws[bh * 8 + 4 + tid] = L;
    }
}

// ---------------- v-pass: copy v_cache -> v_out, weight with global (m,l), write attn ------
__global__ __launch_bounds__(1024) void v_pass(const float* __restrict__ v_cache,
                                               const float* __restrict__ qkv,
                                               const float* __restrict__ ml_ws,
                                               const f4* __restrict__ s_ws,
                                               float* __restrict__ v_out,
                                               float* __restrict__ attn_out) {
    const int bh = blockIdx.x;
    const int b = bh >> 4;
    const int h = bh & 15;
    const int tid = threadIdx.x;
    const int slot = tid >> 4;
    const int quad = tid & 15;

    float m[4], linv[4];
#pragma unroll
    for (int qs = 0; qs < 4; ++qs) {
        m[qs] = ml_ws[bh * 8 + qs];
        linv[qs] = 1.0f / ml_ws[bh * 8 + 4 + qs];
    }

    const f4* vc = reinterpret_cast<const f4*>(v_cache + (size_t)bh * CACHE_LEN * HDIM);
    f4* vo = reinterpret_cast<f4*>(v_out + (size_t)bh * TOT_LEN * HDIM);
    const f4* sb = s_ws + (size_t)bh * S_STRIDE;

    float acc[4][4];
#pragma unroll
    for (int qs = 0; qs < 4; ++qs) acc[qs][0] = acc[qs][1] = acc[qs][2] = acc[qs][3] = 0.f;

    for (int g = 0; g < CACHE_LEN / 256; ++g) {
        f4 vv[4], s4[4];
        int fi[4];
#pragma unroll
        for (int j = 0; j < 4; ++j) {
            const int key = g * 256 + j * 64 + slot;
            fi[j] = key * 16 + quad;
            vv[j] = __builtin_nontemporal_load(vc + fi[j]);
        }
#pragma unroll
        for (int j = 0; j < 4; ++j) s4[j] = __builtin_nontemporal_load(sb + g * 256 + j * 64 + slot);
#pragma unroll
        for (int j = 0; j < 4; ++j) __builtin_nontemporal_store(vv[j], vo + fi[j]);
#pragma unroll
        for (int j = 0; j < 4; ++j) {
#pragma unroll
            for (int qs = 0; qs < 4; ++qs) {
                const float w = __expf(s4[j][qs] - m[qs]);
                acc[qs][0] += w * vv[j].x;
                acc[qs][1] += w * vv[j].y;
                acc[qs][2] += w * vv[j].z;
                acc[qs][3] += w * vv[j].w;
            }
        }
    }

    // Tail: 4 new values from qkv (wave 0 only)
    if (slot < 4) {
        const int key = CACHE_LEN + slot;
        const f4 v4 = *reinterpret_cast<const f4*>(
            qkv + (size_t)(b * SEQ + slot) * 3072 + 2048 + h * HDIM + quad * 4);
        vo[key * 16 + quad] = v4;
        const f4 s4 = sb[CACHE_LEN + slot];
#pragma unroll
        for (int qs = 0; qs < 4; ++qs) {
            const float w = __expf(s4[qs] - m[qs]);
            acc[qs][0] += w * v4.x;
            acc[qs][1] += w * v4.y;
            acc[qs][2] += w * v4.z;
            acc[qs][3] += w * v4.w;
        }
    }

    // Merge 64 per-slot partial accumulators, divide by l, write attn_out.
    __shared__ float red_acc[64][64];
    __shared__ float red_part[4][64];
    for (int qs = 0; qs < 4; ++qs) {
        __syncthreads();
        *reinterpret_cast<f4*>(&red_acc[slot][quad * 4]) =
            (f4){acc[qs][0], acc[qs][1], acc[qs][2], acc[qs][3]};
        __syncthreads();
        if (tid < 256) {
            const int dim = tid & 63;
            const int part = tid >> 6;
            float sum = 0.f;
            for (int s2 = 0; s2 < 16; ++s2) sum += red_acc[part * 16 + s2][dim];
            red_part[part][dim] = sum;
        }
        __syncthreads();
        if (tid < 64) {
            const float sum =
                red_part[0][tid] + red_part[1][tid] + red_part[2][tid] + red_part[3][tid];
            attn_out[(size_t)(b * SEQ + qs) * 1024 + h * HDIM + tid] = sum * linv[qs];
        }
    }
}

extern "C" void kernel_launch(void* const* d_in, const int* in_sizes, int n_in,
                              void* d_out, int out_size, void* d_ws, size_t ws_size,
                              hipStream_t stream) {
    const float* x       = (const float*)d_in[0];
    const float* k_cache = (const float*)d_in[1];
    const float* v_cache = (const float*)d_in[2];
    const float* W_in    = (const float*)d_in[3];
    const float* b_in    = (const float*)d_in[4];
    const float* W_out   = (const float*)d_in[5];
    const float* b_out   = (const float*)d_in[6];

    float* out   = (float*)d_out;                                   // [16,4,1024]
    float* k_out = out + (size_t)BATCH * SEQ * 1024;                // [16,16,8196,64]
    float* v_out = k_out + (size_t)BATCH * NHEAD * TOT_LEN * HDIM;  // [16,16,8196,64]

    float* ws_qkv  = (float*)d_ws;                     // [64,3072]  (768 KB)
    float* ws_attn = ws_qkv + 64 * 3072;               // [64,1024]  (256 KB)
    float* ml_ws   = ws_attn + 64 * 1024;              // [256,8]    (8 KB)
    f4*    s_ws    = (f4*)(ml_ws + 256 * 8);           // [256,S_STRIDE] f4 (~33.6 MB)

    gemm64<3072><<<dim3(48, 8), 256, 0, stream>>>(x, W_in, b_in, ws_qkv);
    k_pass<<<dim3(256), 1024, 0, stream>>>(k_cache, ws_qkv, k_out, s_ws, ml_ws);
    v_pass<<<dim3(256), 1024, 0, stream>>>(v_cache, ws_qkv, ml_ws, s_ws, v_out, ws_attn);
    gemm64<1024><<<dim3(16, 8), 256, 0, stream>>>(ws_attn, W_out, b_out, out);
}